// Round 2
// baseline (535.707 us; speedup 1.0000x reference)
//
#include <hip/hip_runtime.h>

// Resize3D nearest, half-pixel centers.  (Round 2: identical to round 1 —
// that bench died to a container-acquisition flake, not a kernel verdict.)
// in : (2, 64, 128, 128, 16) f32   (134 MB)
// out: (2, 96, 192, 192, 16) f32   (453 MB)
// All three resized axes: src = floor((dst + 0.5) * 2/3) = (2*dst + 1) / 3.
//
// One block owns FOUR output rows (b,d,h fixed), so b/d/sd/sh are
// wave-uniform scalars (SGPR) and the per-element index math collapses to
// {w = r>>2, c4 = r&3, sw = (2w+1)/3} -- ~8 VALU instead of ~35 (no
// %192 / %96 chains per element). The 3 per-thread column offsets are
// shared across all 4 rows. 12 independent loads in flight per thread
// before any store (3x the MLP of the round-0 kernel's 4).
//
// XCD-chunked blockIdx swizzle (9216 blocks = 8 XCDs x 1152, bijective):
// the h-triple / d-triple input reuse (input row feeds up to 3 output rows,
// input slice feeds up to 3 output d's; working set ~2 MB < 4 MB per-XCD L2)
// hits the local L2 instead of round-robining across XCDs into L3.
//
// Stores are nontemporal (write-once 453 MB output; keep the 134 MB input
// resident in L2/L3). Each block writes one contiguous 48 KB chunk.

typedef float f4 __attribute__((ext_vector_type(4)));

#define OUT_D 96u
#define OUT_H 192u
#define OUT_W 192u
#define IN_D 64u
#define IN_H 128u
#define IN_W 128u

// output rows (b,d,h): 2*96*192 = 36864; 4 rows/block -> 9216 blocks
// row = 192 voxels * 4 f4 = 768 f4 (12 KB); block = 3072 f4 (48 KB)
#define N_BLOCKS 9216u
#define BLOCKS_PER_XCD (N_BLOCKS / 8u)   // 1152

__global__ __launch_bounds__(256) void Resize3D_52304111731438_kernel(
    const f4* __restrict__ in, f4* __restrict__ out) {
    // XCD-aware chunked swizzle (bijective since N_BLOCKS % 8 == 0)
    unsigned bid = blockIdx.x;
    bid = (bid & 7u) * BLOCKS_PER_XCD + (bid >> 3);

    const unsigned tid = threadIdx.x;

    // block -> (b, d, h-quad): all wave-uniform -> scalar ops
    unsigned q  = bid % 48u;        // h-quad index within the d-slice (48*4 = 192 rows)
    unsigned bd = bid / 48u;        // (b,d) flattened, < 192
    unsigned d  = bd % 96u;
    unsigned b  = bd / 96u;
    unsigned h0 = q * 4u;
    unsigned sd = (2u * d + 1u) / 3u;   // < 64, no clip needed

    // per-thread column offsets within an input row, shared by all 4 rows
    unsigned off[3];
#pragma unroll
    for (int k = 0; k < 3; ++k) {
        unsigned r  = tid + (unsigned)k * 256u;   // f4 index within output row
        unsigned w  = r >> 2;                     // output voxel w
        unsigned c4 = r & 3u;                     // f4 within the 16-float channel
        unsigned sw = (2u * w + 1u) / 3u;         // < 128
        off[k] = sw * 4u + c4;
    }

    const f4* __restrict__ slice = in + (size_t)(b * IN_D + sd) * (IN_H * IN_W * 4u);
    f4* __restrict__ oblk = out + (size_t)bid * 3072u + tid;

    f4 v[4][3];
#pragma unroll
    for (int row = 0; row < 4; ++row) {
        unsigned h  = h0 + (unsigned)row;
        unsigned sh = (2u * h + 1u) / 3u;         // < 128
        const f4* __restrict__ irow = slice + sh * (IN_W * 4u);
#pragma unroll
        for (int k = 0; k < 3; ++k) v[row][k] = irow[off[k]];
    }

#pragma unroll
    for (int row = 0; row < 4; ++row) {
#pragma unroll
        for (int k = 0; k < 3; ++k) {
            __builtin_nontemporal_store(v[row][k],
                                        &oblk[(unsigned)row * 768u + (unsigned)k * 256u]);
        }
    }
}

extern "C" void kernel_launch(void* const* d_in, const int* in_sizes, int n_in,
                              void* d_out, int out_size, void* d_ws, size_t ws_size,
                              hipStream_t stream) {
    const f4* in = (const f4*)d_in[0];
    f4* out = (f4*)d_out;
    Resize3D_52304111731438_kernel<<<N_BLOCKS, 256, 0, stream>>>(in, out);
}

// Round 3
// 530.808 us; speedup vs baseline: 1.0092x; 1.0092x over previous
//
#include <hip/hip_runtime.h>

// Resize3D nearest, half-pixel centers.
// in : (2, 64, 128, 128, 16) f32   (134 MB)
// out: (2, 96, 192, 192, 16) f32   (453 MB)
// All three resized axes: src = floor((dst + 0.5) * 2/3) = (2*dst + 1) / 3.
//
// ROUND 3 — single-variable experiment: PLAIN stores instead of
// __builtin_nontemporal_store. Evidence: two structurally very different
// kernels (R0: 4 loads/thread, ~35 VALU/elem; R2: 12 loads/thread, ~8
// VALU/elem, XCD swizzle) both land at ~235-250 us of kernel time
// (dur_us minus the ~285 us in-window poison fill). Neither VALU nor MLP
// is the wall. The shared untested element is the NT store path for all
// 453 MB of output; the harness fills and the m13 copy ceiling both reach
// 6.3 TB/s with PLAIN stores. Theory: nt (L2-bypass write-through) drains
// at a fraction of the cached-store rate. Wave stores here are contiguous
// full 1 KB segments, so write-allocate costs no read-for-ownership.
//
// Everything else identical to round 2:
//  - one block = 4 output rows (b,d,h fixed): b/d/sd/sh wave-uniform SGPR
//  - 3 per-thread column offsets shared across the 4 rows
//  - 12 independent loads in flight per thread before any store
//  - XCD-chunked bijective swizzle (9216 = 8 x 1152) for input L2 locality

typedef float f4 __attribute__((ext_vector_type(4)));

#define OUT_D 96u
#define OUT_H 192u
#define OUT_W 192u
#define IN_D 64u
#define IN_H 128u
#define IN_W 128u

// output rows (b,d,h): 2*96*192 = 36864; 4 rows/block -> 9216 blocks
// row = 192 voxels * 4 f4 = 768 f4 (12 KB); block = 3072 f4 (48 KB)
#define N_BLOCKS 9216u
#define BLOCKS_PER_XCD (N_BLOCKS / 8u)   // 1152

__global__ __launch_bounds__(256) void Resize3D_52304111731438_kernel(
    const f4* __restrict__ in, f4* __restrict__ out) {
    // XCD-aware chunked swizzle (bijective since N_BLOCKS % 8 == 0)
    unsigned bid = blockIdx.x;
    bid = (bid & 7u) * BLOCKS_PER_XCD + (bid >> 3);

    const unsigned tid = threadIdx.x;

    // block -> (b, d, h-quad): all wave-uniform -> scalar ops
    unsigned q  = bid % 48u;        // h-quad index within the d-slice (48*4 = 192 rows)
    unsigned bd = bid / 48u;        // (b,d) flattened, < 192
    unsigned d  = bd % 96u;
    unsigned b  = bd / 96u;
    unsigned h0 = q * 4u;
    unsigned sd = (2u * d + 1u) / 3u;   // < 64, no clip needed

    // per-thread column offsets within an input row, shared by all 4 rows
    unsigned off[3];
#pragma unroll
    for (int k = 0; k < 3; ++k) {
        unsigned r  = tid + (unsigned)k * 256u;   // f4 index within output row
        unsigned w  = r >> 2;                     // output voxel w
        unsigned c4 = r & 3u;                     // f4 within the 16-float channel
        unsigned sw = (2u * w + 1u) / 3u;         // < 128
        off[k] = sw * 4u + c4;
    }

    const f4* __restrict__ slice = in + (size_t)(b * IN_D + sd) * (IN_H * IN_W * 4u);
    f4* __restrict__ oblk = out + (size_t)bid * 3072u + tid;

    f4 v[4][3];
#pragma unroll
    for (int row = 0; row < 4; ++row) {
        unsigned h  = h0 + (unsigned)row;
        unsigned sh = (2u * h + 1u) / 3u;         // < 128
        const f4* __restrict__ irow = slice + sh * (IN_W * 4u);
#pragma unroll
        for (int k = 0; k < 3; ++k) v[row][k] = irow[off[k]];
    }

#pragma unroll
    for (int row = 0; row < 4; ++row) {
#pragma unroll
        for (int k = 0; k < 3; ++k) {
            oblk[(unsigned)row * 768u + (unsigned)k * 256u] = v[row][k];
        }
    }
}

extern "C" void kernel_launch(void* const* d_in, const int* in_sizes, int n_in,
                              void* d_out, int out_size, void* d_ws, size_t ws_size,
                              hipStream_t stream) {
    const f4* in = (const f4*)d_in[0];
    f4* out = (f4*)d_out;
    Resize3D_52304111731438_kernel<<<N_BLOCKS, 256, 0, stream>>>(in, out);
}

// Round 5
// 528.971 us; speedup vs baseline: 1.0127x; 1.0035x over previous
//
#include <hip/hip_runtime.h>

// Resize3D nearest, half-pixel centers.  (Round 5: identical to round 4 —
// that bench died to the same container-acquisition flake as round 1,
// which passed on identical resubmission. Not a kernel verdict.)
// in : (2, 64, 128, 128, 16) f32   (134 MB)
// out: (2, 96, 192, 192, 16) f32   (453 MB)
// src = floor((dst + 0.5) * 2/3) = (2*dst + 1) / 3 on all three axes.
//
// Experiment: eliminate the HBM gather.
// R0-R3 falsified stores (NT==plain), VALU count, and MLP as the wall:
// three very different kernels all ran ~243 us (dur_us minus the ~287 us
// in-window poison fill) = 2.4 TB/s effective. The one shared element was
// the duplicated 16B-granular gather read of the input. This version:
//   - each block owns 4 output rows (b,d fixed, h = 4q..4q+3), which need
//     EXACTLY 3 contiguous input rows: sh(4q+r) = (8q+2r+1)/3 spans
//     s0 = (8q+1)/3 .. s0+2 for every q.
//   - stage those 3 rows (1536 f4 = 24 KB) into LDS via
//     __builtin_amdgcn_global_load_lds width=16: HBM reads are contiguous,
//     unique, 16 B/lane coalesced (the builtin's LDS dest is wave-uniform
//     base + lane*16 -> linear LDS, exactly our layout).
//   - the (2w+1)/3 column gather moves to ds_read_b128 from LDS
//     (monotonic dup-pair pattern over a 688 B span: ~2-way bank aliasing,
//     free per m136).
//   - stores unchanged: contiguous 48 KB/block, plain (NT falsified in R3).
// LDS 24 KB -> 6 blocks/CU (24 waves/CU), fine for a streaming kernel.

typedef float f4 __attribute__((ext_vector_type(4)));
typedef const __attribute__((address_space(1))) unsigned int GAS;
typedef __attribute__((address_space(3))) unsigned int LAS;

#define N_BLOCKS 9216u                  // 2*96*192 output rows / 4 rows per block
#define BLOCKS_PER_XCD (N_BLOCKS / 8u)  // 1152

__global__ __launch_bounds__(256) void Resize3D_52304111731438_kernel(
    const f4* __restrict__ in, f4* __restrict__ out) {
    __shared__ f4 lds[1536];            // 3 input rows x 512 f4 = 24 KB

    // XCD-aware chunked swizzle (bijective: 9216 % 8 == 0)
    unsigned bid = blockIdx.x;
    bid = (bid & 7u) * BLOCKS_PER_XCD + (bid >> 3);

    const unsigned tid  = threadIdx.x;
    const unsigned wave = tid >> 6;
    const unsigned lane = tid & 63u;

    // block -> (b, d, h-quad); all wave-uniform
    unsigned q  = bid % 48u;            // h-quad within the (b,d) plane
    unsigned bd = bid / 48u;
    unsigned d  = bd % 96u;
    unsigned b  = bd / 96u;
    unsigned sd = (2u * d + 1u) / 3u;   // < 64
    unsigned s0 = (8u * q + 1u) / 3u;   // first of the 3 input rows, s0+2 <= 127

    const f4* __restrict__ slice =
        in + (size_t)(b * 64u + sd) * 65536u + (size_t)s0 * 512u;

    // ---- stage 3 contiguous input rows -> LDS (issue memory first) ----
    // 1536 f4 = 24 wave-calls of 1 KB; wave i takes chunks c = i*6..i*6+5.
#pragma unroll
    for (unsigned k = 0; k < 6u; ++k) {
        unsigned c = wave * 6u + k;     // wave-uniform chunk id
        __builtin_amdgcn_global_load_lds(
            (GAS*)(const void*)(slice + c * 64u + lane),
            (LAS*)(void*)(lds + c * 64u),
            16, 0, 0);
    }

    // ---- VALU while loads fly: column offsets shared by all 4 rows ----
    unsigned off[3];
#pragma unroll
    for (int k = 0; k < 3; ++k) {
        unsigned r  = tid + (unsigned)k * 256u;  // f4 index within output row
        unsigned w  = r >> 2;
        unsigned c4 = r & 3u;
        unsigned sw = (2u * w + 1u) / 3u;        // < 128
        off[k] = sw * 4u + c4;
    }

    __syncthreads();   // compiler drains vmcnt(0) here (global_load_lds done)

    // ---- gather from LDS, store contiguous ----
    f4 v[4][3];
#pragma unroll
    for (int r = 0; r < 4; ++r) {
        unsigned lh = (8u * q + 2u * (unsigned)r + 1u) / 3u - s0;  // 0..2
        const f4* lrow = lds + lh * 512u;
#pragma unroll
        for (int k = 0; k < 3; ++k) v[r][k] = lrow[off[k]];
    }

    f4* __restrict__ oblk = out + (size_t)bid * 3072u + tid;
#pragma unroll
    for (int r = 0; r < 4; ++r) {
#pragma unroll
        for (int k = 0; k < 3; ++k) {
            oblk[(unsigned)r * 768u + (unsigned)k * 256u] = v[r][k];
        }
    }
}

extern "C" void kernel_launch(void* const* d_in, const int* in_sizes, int n_in,
                              void* d_out, int out_size, void* d_ws, size_t ws_size,
                              hipStream_t stream) {
    const f4* in = (const f4*)d_in[0];
    f4* out = (f4*)d_out;
    Resize3D_52304111731438_kernel<<<N_BLOCKS, 256, 0, stream>>>(in, out);
}